// Round 5
// baseline (265.874 us; speedup 1.0000x reference)
//
#include <hip/hip_runtime.h>

#define N_NODES 50000
#define N_EDGES 800000
#define CH 64
#define OUT_OFF_STD (N_NODES * CH)        // 3,200,000
#define OUT_OFF_KL  (2 * N_NODES * CH)    // 6,400,000
#define CAP 64                            // slots/node; in-degree ~Poisson(16)

__device__ __forceinline__ int rl_i(unsigned v, int lane) {
    return __builtin_amdgcn_readlane((int)v, lane);
}
__device__ __forceinline__ float rl_f(unsigned v, int lane) {
    return __uint_as_float((unsigned)__builtin_amdgcn_readlane((int)v, lane));
}

// ---------------------------------------------------------------------------
// Kernel A: reparameterized weights (stored TRANSPOSED: wt[c*64+k] = W[k][c])
// + KL reduction. One block, 256 threads.
// ---------------------------------------------------------------------------
__global__ __launch_bounds__(256) void wkl_kernel(
    const float* __restrict__ mu_m, const float* __restrict__ ls_m,
    const float* __restrict__ eps_m,
    const float* __restrict__ mu_s, const float* __restrict__ ls_s,
    const float* __restrict__ eps_s,
    float* __restrict__ wt_m, float* __restrict__ wt_s,
    float* __restrict__ kl_out)
{
    float kl = 0.0f;
    for (int i = threadIdx.x; i < CH * CH; i += 256) {
        int k = i >> 6, c = i & 63;
        float mu = mu_m[i], ls = ls_m[i];
        wt_m[c * 64 + k] = mu + eps_m[i] * expf(ls);
        kl += 0.5f * (expf(2.0f * ls) + mu * mu - 2.0f * ls - 1.0f);
        mu = mu_s[i]; ls = ls_s[i];
        wt_s[c * 64 + k] = mu + eps_s[i] * expf(ls);
        kl += 0.5f * (expf(2.0f * ls) + mu * mu - 2.0f * ls - 1.0f);
    }
    for (int off = 32; off > 0; off >>= 1)
        kl += __shfl_down(kl, off, 64);
    __shared__ float red[4];
    if ((threadIdx.x & 63) == 0) red[threadIdx.x >> 6] = kl;
    __syncthreads();
    if (threadIdx.x == 0)
        kl_out[0] = red[0] + red[1] + red[2] + red[3];
}

// ---------------------------------------------------------------------------
// Kernel B: fill (bin edges per dst, fixed CAP) + pack xpack[i]={mean,std^2}.
// Grid exactly covers 800000 edges; pack grid-strides 3.2M elements (4 iters).
// ---------------------------------------------------------------------------
__global__ __launch_bounds__(256) void fillpack_kernel(
    const int* __restrict__ ei, const float* __restrict__ ew,
    const float* __restrict__ mean, const float* __restrict__ stdv,
    int* __restrict__ cur, uint2* __restrict__ bins,
    float2* __restrict__ xpack)
{
    const int t = blockIdx.x * 256 + threadIdx.x;   // 0 .. 799999
    // pack: xpack[i] = {mean_i, std_i^2}, coalesced float2 stores
    for (int i = t; i < N_NODES * CH; i += N_EDGES) {
        float m = mean[i];
        float s = stdv[i];
        xpack[i] = make_float2(m, s * s);
    }
    // fill: one edge per thread
    int src = ei[t];
    int dst = ei[N_EDGES + t];
    float w = ew[t];
    int slot = atomicAdd(&cur[dst], 1);
    if (slot < CAP)
        bins[(size_t)dst * CAP + slot] = make_uint2((unsigned)src,
                                                    __float_as_uint(w));
}

// ---------------------------------------------------------------------------
// Kernel C: mega = pull-gather (on X, by linearity) + fused per-tile GEMM +
// epilogue. 16 nodes/block, 4 nodes/wave, lane = channel.
//  - gather: branch-free selects -> 4 independent 8B loads in flight per iter
//  - GEMV: readlane-broadcast of in-register aggregates vs b128 W-frags (LDS)
//  - no global atomics, output written once.
// ---------------------------------------------------------------------------
__global__ __launch_bounds__(256) void mega_kernel(
    const int* __restrict__ cur, const uint2* __restrict__ bins,
    const float2* __restrict__ xpack,
    const float* __restrict__ wt_m_g, const float* __restrict__ wt_s_g,
    float* __restrict__ out)
{
    __shared__ float Wt_m[64 * 68];   // [c][k], stride 68: linear-write
    __shared__ float Wt_v[64 * 68];   //   conflict-free, b128-read aligned
    for (int i = threadIdx.x; i < CH * CH; i += 256) {
        int c = i >> 6, k = i & 63;
        Wt_m[c * 68 + k] = wt_m_g[i];
        Wt_v[c * 68 + k] = wt_s_g[i];
    }

    const int wv = threadIdx.x >> 6;
    const int col = threadIdx.x & 63;
    const int nb = blockIdx.x * 16 + wv * 4;

    // preload payloads (coalesced 512B per node) and counts
    uint2 p0 = bins[(size_t)(nb + 0) * CAP + col];
    uint2 p1 = bins[(size_t)(nb + 1) * CAP + col];
    uint2 p2 = bins[(size_t)(nb + 2) * CAP + col];
    uint2 p3 = bins[(size_t)(nb + 3) * CAP + col];
    int c0 = cur[nb + 0]; c0 = c0 > CAP ? CAP : c0;
    int c1 = cur[nb + 1]; c1 = c1 > CAP ? CAP : c1;
    int c2 = cur[nb + 2]; c2 = c2 > CAP ? CAP : c2;
    int c3 = cur[nb + 3]; c3 = c3 > CAP ? CAP : c3;
    int mx = max(max(c0, c1), max(c2, c3));

    float aM0 = 0, aM1 = 0, aM2 = 0, aM3 = 0;
    float aV0 = 0, aV1 = 0, aV2 = 0, aV3 = 0;
    for (int i = 0; i < mx; ++i) {
        // sanitized selects: idle slots read node 0 with weight 0 (no branch)
        int s0 = (i < c0) ? rl_i(p0.x, i) : 0;
        int s1 = (i < c1) ? rl_i(p1.x, i) : 0;
        int s2 = (i < c2) ? rl_i(p2.x, i) : 0;
        int s3 = (i < c3) ? rl_i(p3.x, i) : 0;
        float w0 = (i < c0) ? rl_f(p0.y, i) : 0.0f;
        float w1 = (i < c1) ? rl_f(p1.y, i) : 0.0f;
        float w2 = (i < c2) ? rl_f(p2.y, i) : 0.0f;
        float w3 = (i < c3) ? rl_f(p3.y, i) : 0.0f;
        float2 x0 = xpack[(size_t)s0 * CH + col];
        float2 x1 = xpack[(size_t)s1 * CH + col];
        float2 x2 = xpack[(size_t)s2 * CH + col];
        float2 x3 = xpack[(size_t)s3 * CH + col];
        aM0 += w0 * x0.x;  aV0 += (w0 * w0) * x0.y;
        aM1 += w1 * x1.x;  aV1 += (w1 * w1) * x1.y;
        aM2 += w2 * x2.x;  aV2 += (w2 * w2) * x2.y;
        aM3 += w3 * x3.x;  aV3 += (w3 * w3) * x3.y;
    }

    __syncthreads();   // Wt staging complete before GEMV reads

    // GEMV: out[n][col] = sum_k agg[n][k] * W[k][col].
    // agg[n][k] lives in lane k of aM/aV -> readlane broadcast (SGPR).
    float oM0 = 0, oM1 = 0, oM2 = 0, oM3 = 0;
    float oV0 = 0, oV1 = 0, oV2 = 0, oV3 = 0;
#pragma unroll
    for (int k4 = 0; k4 < 16; ++k4) {
        float4 wm = *(const float4*)&Wt_m[col * 68 + k4 * 4];
        float4 wv4 = *(const float4*)&Wt_v[col * 68 + k4 * 4];
        const float* wmp = &wm.x;
        const float* wvp = &wv4.x;
#pragma unroll
        for (int t = 0; t < 4; ++t) {
            const int k = k4 * 4 + t;
            float wmk = wmp[t], wvk = wvp[t];
            oM0 += __uint_as_float((unsigned)__builtin_amdgcn_readlane(__float_as_int(aM0), k)) * wmk;
            oM1 += __uint_as_float((unsigned)__builtin_amdgcn_readlane(__float_as_int(aM1), k)) * wmk;
            oM2 += __uint_as_float((unsigned)__builtin_amdgcn_readlane(__float_as_int(aM2), k)) * wmk;
            oM3 += __uint_as_float((unsigned)__builtin_amdgcn_readlane(__float_as_int(aM3), k)) * wmk;
            oV0 += __uint_as_float((unsigned)__builtin_amdgcn_readlane(__float_as_int(aV0), k)) * wvk;
            oV1 += __uint_as_float((unsigned)__builtin_amdgcn_readlane(__float_as_int(aV1), k)) * wvk;
            oV2 += __uint_as_float((unsigned)__builtin_amdgcn_readlane(__float_as_int(aV2), k)) * wvk;
            oV3 += __uint_as_float((unsigned)__builtin_amdgcn_readlane(__float_as_int(aV3), k)) * wvk;
        }
    }

    // epilogue + single clean write
    size_t r0 = (size_t)(nb + 0) * CH + col;
    out[r0]            = oM0;
    out[r0 + CH]       = oM1;
    out[r0 + 2 * CH]   = oM2;
    out[r0 + 3 * CH]   = oM3;
    out[OUT_OFF_STD + r0]          = sqrtf(expf(oV0) + 1e-6f);
    out[OUT_OFF_STD + r0 + CH]     = sqrtf(expf(oV1) + 1e-6f);
    out[OUT_OFF_STD + r0 + 2 * CH] = sqrtf(expf(oV2) + 1e-6f);
    out[OUT_OFF_STD + r0 + 3 * CH] = sqrtf(expf(oV3) + 1e-6f);
}

extern "C" void kernel_launch(void* const* d_in, const int* in_sizes, int n_in,
                              void* d_out, int out_size, void* d_ws, size_t ws_size,
                              hipStream_t stream)
{
    const float* mean  = (const float*)d_in[0];
    const float* stdv  = (const float*)d_in[1];
    const int*   ei    = (const int*)d_in[2];
    const float* ew    = (const float*)d_in[3];
    const float* mu_m  = (const float*)d_in[4];
    const float* ls_m  = (const float*)d_in[5];
    const float* eps_m = (const float*)d_in[6];
    const float* mu_s  = (const float*)d_in[7];
    const float* ls_s  = (const float*)d_in[8];
    const float* eps_s = (const float*)d_in[9];

    float* out = (float*)d_out;
    float* ws  = (float*)d_ws;
    float*  wt_m  = ws;                                   // 4096 f
    float*  wt_s  = ws + 4096;                            // 4096 f
    int*    cur   = (int*)(ws + 8192);                    // 50000 i
    float2* xpack = (float2*)(ws + 8192 + 50000);         // 3.2M float2 (25.6MB)
    uint2*  bins  = (uint2*)(ws + 8192 + 50000 + 6400000);// 3.2M uint2  (25.6MB)

    hipMemsetAsync(cur, 0, N_NODES * sizeof(int), stream);

    wkl_kernel<<<1, 256, 0, stream>>>(mu_m, ls_m, eps_m, mu_s, ls_s, eps_s,
                                      wt_m, wt_s, out + OUT_OFF_KL);
    fillpack_kernel<<<N_EDGES / 256, 256, 0, stream>>>(ei, ew, mean, stdv,
                                                       cur, bins, xpack);
    mega_kernel<<<N_NODES / 16, 256, 0, stream>>>(cur, bins, xpack,
                                                  wt_m, wt_s, out);
}

// Round 6
// 227.923 us; speedup vs baseline: 1.1665x; 1.1665x over previous
//
#include <hip/hip_runtime.h>

#define N_NODES 50000
#define N_EDGES 800000
#define CH 64
#define OUT_OFF_STD (N_NODES * CH)        // 3,200,000
#define OUT_OFF_KL  (2 * N_NODES * CH)    // 6,400,000
#define CAP 64                            // slots/node; in-degree ~Poisson(16)

__device__ __forceinline__ int rl_i(unsigned v, int lane) {
    return __builtin_amdgcn_readlane((int)v, lane);
}
__device__ __forceinline__ float rl_f(unsigned v, int lane) {
    return __uint_as_float((unsigned)__builtin_amdgcn_readlane((int)v, lane));
}

// ---------------------------------------------------------------------------
// Kernel A: reparameterized weights + KL reduction. One block, 256 threads.
// ---------------------------------------------------------------------------
__global__ __launch_bounds__(256) void wkl_kernel(
    const float* __restrict__ mu_m, const float* __restrict__ ls_m,
    const float* __restrict__ eps_m,
    const float* __restrict__ mu_s, const float* __restrict__ ls_s,
    const float* __restrict__ eps_s,
    float* __restrict__ w_m, float* __restrict__ w_s,
    float* __restrict__ kl_out)
{
    float kl = 0.0f;
    for (int i = threadIdx.x; i < CH * CH; i += 256) {
        float mu = mu_m[i], ls = ls_m[i];
        w_m[i] = mu + eps_m[i] * expf(ls);
        kl += 0.5f * (expf(2.0f * ls) + mu * mu - 2.0f * ls - 1.0f);
        mu = mu_s[i]; ls = ls_s[i];
        w_s[i] = mu + eps_s[i] * expf(ls);
        kl += 0.5f * (expf(2.0f * ls) + mu * mu - 2.0f * ls - 1.0f);
    }
    for (int off = 32; off > 0; off >>= 1)
        kl += __shfl_down(kl, off, 64);
    __shared__ float red[4];
    if ((threadIdx.x & 63) == 0) red[threadIdx.x >> 6] = kl;
    __syncthreads();
    if (threadIdx.x == 0)
        kl_out[0] = red[0] + red[1] + red[2] + red[3];
}

// ---------------------------------------------------------------------------
// Kernel B: fused gemm+fill, block-parity roles (overlaps LDS-pipe-bound
// GEMM with memory-latency-bound fill on the same CUs).
//  even blocks: 16-row dual-GEMM tile -> sup2[row*64+col] = {mean,var}
//  odd  blocks: 256-edge fill chunk   -> bins/cur (low-contention atomics)
// ---------------------------------------------------------------------------
__global__ __launch_bounds__(256) void gemfill_kernel(
    const float* __restrict__ mean, const float* __restrict__ stdv,
    const float* __restrict__ w_m_g, const float* __restrict__ w_s_g,
    const int* __restrict__ ei, const float* __restrict__ ew,
    int* __restrict__ cur, uint2* __restrict__ bins,
    float2* __restrict__ sup2)
{
    __shared__ float Wt_m[64 * 68];     // Wt[col][k], stride 68: b128-aligned
    __shared__ float Wt_v[64 * 68];
    __shared__ float Xm[16 * 64];
    __shared__ float Xs[16 * 64];       // std^2

    const int tid = threadIdx.x;

    if (blockIdx.x & 1) {               // ---- fill role ----
        int e = (blockIdx.x >> 1) * 256 + tid;   // 3125*256 = 800000 exact
        int src = ei[e];
        int dst = ei[N_EDGES + e];
        float w = ew[e];
        int slot = atomicAdd(&cur[dst], 1);
        if (slot < CAP)
            bins[(size_t)dst * CAP + slot] =
                make_uint2((unsigned)src, __float_as_uint(w));
        return;
    }

    // ---- gemm role ----
    for (int i = tid; i < CH * CH; i += 256) {
        int k = i >> 6, c = i & 63;
        Wt_m[c * 68 + k] = w_m_g[i];
        Wt_v[c * 68 + k] = w_s_g[i];
    }
    const int row0 = (blockIdx.x >> 1) * 16;
    const float4* m4p = (const float4*)(mean + (size_t)row0 * CH);
    const float4* s4p = (const float4*)(stdv + (size_t)row0 * CH);
    float4* Xm4 = (float4*)Xm;
    float4* Xs4 = (float4*)Xs;
    {
        int i = tid;                    // 16 rows * 16 float4 = 256
        Xm4[i] = m4p[i];
        float4 s = s4p[i];
        s.x *= s.x; s.y *= s.y; s.z *= s.z; s.w *= s.w;
        Xs4[i] = s;
    }
    __syncthreads();

    const int wave = tid >> 6, col = tid & 63;
    const int r0 = wave * 4;

    float am0 = 0, am1 = 0, am2 = 0, am3 = 0;
    float av0 = 0, av1 = 0, av2 = 0, av3 = 0;
#pragma unroll
    for (int k4 = 0; k4 < 16; ++k4) {
        float4 wm = *(const float4*)&Wt_m[col * 68 + k4 * 4];
        float4 wv = *(const float4*)&Wt_v[col * 68 + k4 * 4];
        float4 x0 = *(const float4*)&Xm[(r0 + 0) * 64 + k4 * 4];
        float4 x1 = *(const float4*)&Xm[(r0 + 1) * 64 + k4 * 4];
        float4 x2 = *(const float4*)&Xm[(r0 + 2) * 64 + k4 * 4];
        float4 x3 = *(const float4*)&Xm[(r0 + 3) * 64 + k4 * 4];
        am0 += x0.x * wm.x + x0.y * wm.y + x0.z * wm.z + x0.w * wm.w;
        am1 += x1.x * wm.x + x1.y * wm.y + x1.z * wm.z + x1.w * wm.w;
        am2 += x2.x * wm.x + x2.y * wm.y + x2.z * wm.z + x2.w * wm.w;
        am3 += x3.x * wm.x + x3.y * wm.y + x3.z * wm.z + x3.w * wm.w;
        float4 y0 = *(const float4*)&Xs[(r0 + 0) * 64 + k4 * 4];
        float4 y1 = *(const float4*)&Xs[(r0 + 1) * 64 + k4 * 4];
        float4 y2 = *(const float4*)&Xs[(r0 + 2) * 64 + k4 * 4];
        float4 y3 = *(const float4*)&Xs[(r0 + 3) * 64 + k4 * 4];
        av0 += y0.x * wv.x + y0.y * wv.y + y0.z * wv.z + y0.w * wv.w;
        av1 += y1.x * wv.x + y1.y * wv.y + y1.z * wv.z + y1.w * wv.w;
        av2 += y2.x * wv.x + y2.y * wv.y + y2.z * wv.z + y2.w * wv.w;
        av3 += y3.x * wv.x + y3.y * wv.y + y3.z * wv.z + y3.w * wv.w;
    }
    size_t rb = (size_t)(row0 + r0) * CH + col;
    sup2[rb + 0 * CH] = make_float2(am0, av0);
    sup2[rb + 1 * CH] = make_float2(am1, av1);
    sup2[rb + 2 * CH] = make_float2(am2, av2);
    sup2[rb + 3 * CH] = make_float2(am3, av3);
}

// ---------------------------------------------------------------------------
// Kernel C: pull-gather. One wave per node, lane = channel. Exec-masked bins
// preload (only cnt lanes fetch), unroll-4 with branch-free readlane
// broadcasts (wave-uniform index -> VALU only), 4 independent dwordx2 loads
// in flight. Output written once, epilogue fused. No global atomics, no LDS.
// ---------------------------------------------------------------------------
__global__ __launch_bounds__(256) void gather_kernel(
    const int* __restrict__ cur, const uint2* __restrict__ bins,
    const float2* __restrict__ sup2, float* __restrict__ out)
{
    const int wave = threadIdx.x >> 6;
    const int col = threadIdx.x & 63;
    const int n = blockIdx.x * 4 + wave;

    int cnt = cur[n];
    if (cnt > CAP) cnt = CAP;
    uint2 p = make_uint2(0u, 0u);
    if (col < cnt) p = bins[(size_t)n * CAP + col];

    float accM = 0.0f, accV = 0.0f;
    for (int i = 0; i < cnt; i += 4) {
        const bool v1 = (i + 1 < cnt), v2 = (i + 2 < cnt), v3 = (i + 3 < cnt);
        int s0 = rl_i(p.x, i);
        int s1 = v1 ? rl_i(p.x, i + 1) : 0;
        int s2 = v2 ? rl_i(p.x, i + 2) : 0;
        int s3 = v3 ? rl_i(p.x, i + 3) : 0;
        float w0 = rl_f(p.y, i);
        float w1 = v1 ? rl_f(p.y, i + 1) : 0.0f;
        float w2 = v2 ? rl_f(p.y, i + 2) : 0.0f;
        float w3 = v3 ? rl_f(p.y, i + 3) : 0.0f;
        float2 x0 = sup2[(size_t)s0 * CH + col];
        float2 x1 = sup2[(size_t)s1 * CH + col];
        float2 x2 = sup2[(size_t)s2 * CH + col];
        float2 x3 = sup2[(size_t)s3 * CH + col];
        accM += w0 * x0.x + w1 * x1.x;
        accM += w2 * x2.x + w3 * x3.x;
        accV += (w0 * w0) * x0.y + (w1 * w1) * x1.y;
        accV += (w2 * w2) * x2.y + (w3 * w3) * x3.y;
    }
    out[(size_t)n * CH + col] = accM;
    out[OUT_OFF_STD + (size_t)n * CH + col] = sqrtf(expf(accV) + 1e-6f);
}

extern "C" void kernel_launch(void* const* d_in, const int* in_sizes, int n_in,
                              void* d_out, int out_size, void* d_ws, size_t ws_size,
                              hipStream_t stream)
{
    const float* mean  = (const float*)d_in[0];
    const float* stdv  = (const float*)d_in[1];
    const int*   ei    = (const int*)d_in[2];
    const float* ew    = (const float*)d_in[3];
    const float* mu_m  = (const float*)d_in[4];
    const float* ls_m  = (const float*)d_in[5];
    const float* eps_m = (const float*)d_in[6];
    const float* mu_s  = (const float*)d_in[7];
    const float* ls_s  = (const float*)d_in[8];
    const float* eps_s = (const float*)d_in[9];

    float* out = (float*)d_out;
    float* ws  = (float*)d_ws;
    float*  w_m  = ws;                                    // 4096 f
    float*  w_s  = ws + 4096;                             // 4096 f
    int*    cur  = (int*)(ws + 8192);                     // 50000 i
    float2* sup2 = (float2*)(ws + 8192 + 50000);          // 3.2M float2 (25.6MB)
    uint2*  bins = (uint2*)(ws + 8192 + 50000 + 6400000); // 3.2M uint2  (25.6MB)

    hipMemsetAsync(cur, 0, N_NODES * sizeof(int), stream);

    wkl_kernel<<<1, 256, 0, stream>>>(mu_m, ls_m, eps_m, mu_s, ls_s, eps_s,
                                      w_m, w_s, out + OUT_OFF_KL);
    gemfill_kernel<<<6250, 256, 0, stream>>>(mean, stdv, w_m, w_s,
                                             ei, ew, cur, bins, sup2);
    gather_kernel<<<N_NODES / 4, 256, 0, stream>>>(cur, bins, sup2, out);
}

// Round 7
// 211.660 us; speedup vs baseline: 1.2561x; 1.0768x over previous
//
#include <hip/hip_runtime.h>

#define N_NODES 50000
#define N_EDGES 800000
#define CH 64
#define OUT_OFF_STD (N_NODES * CH)        // 3,200,000
#define OUT_OFF_KL  (2 * N_NODES * CH)    // 6,400,000
#define CAP 64                            // slots/node; in-degree ~Poisson(16)

__device__ __forceinline__ float rl_f(float v, int lane) {
    return __uint_as_float(
        (unsigned)__builtin_amdgcn_readlane(__float_as_int(v), lane));
}
__device__ __forceinline__ int rl_i(unsigned v, int lane) {
    return __builtin_amdgcn_readlane((int)v, lane);
}
// fp32 -> bf16 with round-to-nearest-even
__device__ __forceinline__ unsigned f2bf(float f) {
    unsigned u = __float_as_uint(f);
    return (u + 0x7fffu + ((u >> 16) & 1u)) >> 16;
}

// ---------------------------------------------------------------------------
// Kernel A: fused gemm + fill (+KL), block-parity roles.
//  even blocks (3125): 16-row dual GEMM tile. W computed INLINE from
//    mu/eps/log_sigma into stride-68 LDS (transposed); X rows held in
//    registers, broadcast via v_readlane (VALU pipe, no LDS). Result packed
//    {bf16 mean_sup, bf16 var_sup} into one dword per (node,ch).
//  odd blocks (3125): 256-edge fill chunk -> per-dst bins (low-contention
//    int atomics). Block 1 additionally reduces the KL scalar.
// LDS = 34.8 KB -> 4 blocks/CU (vs 43 KB / 3 in R6).
// ---------------------------------------------------------------------------
__global__ __launch_bounds__(256) void gemfill_kernel(
    const float* __restrict__ mean, const float* __restrict__ stdv,
    const float* __restrict__ mu_m, const float* __restrict__ ls_m,
    const float* __restrict__ eps_m,
    const float* __restrict__ mu_s, const float* __restrict__ ls_s,
    const float* __restrict__ eps_s,
    const int* __restrict__ ei, const float* __restrict__ ew,
    int* __restrict__ cur, uint2* __restrict__ bins,
    unsigned* __restrict__ sup, float* __restrict__ kl_out)
{
    __shared__ float Wt_m[64 * 68];     // Wt[col][k], stride 68 (b128-aligned)
    __shared__ float Wt_v[64 * 68];

    const int tid = threadIdx.x;

    if (blockIdx.x & 1) {               // ---- fill role ----
        int e = (blockIdx.x >> 1) * 256 + tid;   // 3125*256 = 800000 exact
        int src = ei[e];
        int dst = ei[N_EDGES + e];
        float w = ew[e];
        int slot = atomicAdd(&cur[dst], 1);
        if (slot < CAP)
            bins[(size_t)dst * CAP + slot] =
                make_uint2((unsigned)src, __float_as_uint(w));
        if (blockIdx.x == 1) {          // KL reduction rides along here
            float kl = 0.0f;
            for (int i = tid; i < CH * CH; i += 256) {
                float mu = mu_m[i], ls = ls_m[i];
                kl += 0.5f * (expf(2.0f * ls) + mu * mu - 2.0f * ls - 1.0f);
                mu = mu_s[i]; ls = ls_s[i];
                kl += 0.5f * (expf(2.0f * ls) + mu * mu - 2.0f * ls - 1.0f);
            }
            for (int off = 32; off > 0; off >>= 1)
                kl += __shfl_down(kl, off, 64);
            if ((tid & 63) == 0) Wt_m[tid >> 6] = kl;
            __syncthreads();
            if (tid == 0)
                kl_out[0] = Wt_m[0] + Wt_m[1] + Wt_m[2] + Wt_m[3];
        }
        return;
    }

    // ---- gemm role ----
    // compute reparameterized W inline, transposed into LDS
    for (int i = tid; i < CH * CH; i += 256) {
        int k = i >> 6, c = i & 63;
        Wt_m[c * 68 + k] = mu_m[i] + eps_m[i] * expf(ls_m[i]);
        Wt_v[c * 68 + k] = mu_s[i] + eps_s[i] * expf(ls_s[i]);
    }

    const int wave = tid >> 6, col = tid & 63;
    const int row0 = (blockIdx.x >> 1) * 16 + wave * 4;   // 4 rows per wave

    // X rows in registers: lane `col` holds X[row][col] (coalesced dword loads)
    float xm0 = mean[(size_t)(row0 + 0) * CH + col];
    float xm1 = mean[(size_t)(row0 + 1) * CH + col];
    float xm2 = mean[(size_t)(row0 + 2) * CH + col];
    float xm3 = mean[(size_t)(row0 + 3) * CH + col];
    float t0 = stdv[(size_t)(row0 + 0) * CH + col];
    float t1 = stdv[(size_t)(row0 + 1) * CH + col];
    float t2 = stdv[(size_t)(row0 + 2) * CH + col];
    float t3 = stdv[(size_t)(row0 + 3) * CH + col];
    float xs0 = t0 * t0, xs1 = t1 * t1, xs2 = t2 * t2, xs3 = t3 * t3;

    __syncthreads();

    float am0 = 0, am1 = 0, am2 = 0, am3 = 0;
    float av0 = 0, av1 = 0, av2 = 0, av3 = 0;
#pragma unroll
    for (int k4 = 0; k4 < 16; ++k4) {
        float4 wm = *(const float4*)&Wt_m[col * 68 + k4 * 4];
        float4 wv = *(const float4*)&Wt_v[col * 68 + k4 * 4];
#pragma unroll
        for (int t = 0; t < 4; ++t) {
            const int k = k4 * 4 + t;
            const float wmt = (&wm.x)[t];
            const float wvt = (&wv.x)[t];
            am0 += rl_f(xm0, k) * wmt;
            am1 += rl_f(xm1, k) * wmt;
            am2 += rl_f(xm2, k) * wmt;
            am3 += rl_f(xm3, k) * wmt;
            av0 += rl_f(xs0, k) * wvt;
            av1 += rl_f(xs1, k) * wvt;
            av2 += rl_f(xs2, k) * wvt;
            av3 += rl_f(xs3, k) * wvt;
        }
    }

    // pack {bf16 mean_sup | bf16 var_sup} into one dword per (node, ch)
    size_t rb = (size_t)row0 * CH + col;
    sup[rb + 0 * CH] = f2bf(am0) | (f2bf(av0) << 16);
    sup[rb + 1 * CH] = f2bf(am1) | (f2bf(av1) << 16);
    sup[rb + 2 * CH] = f2bf(am2) | (f2bf(av2) << 16);
    sup[rb + 3 * CH] = f2bf(am3) | (f2bf(av3) << 16);
}

// ---------------------------------------------------------------------------
// Kernel B: pull-gather. One wave per node, lane = channel. Exec-masked bins
// preload, unroll-4 with branch-free readlane broadcasts, 4 independent
// dword loads in flight (half the bytes of R6 via bf16 packing). Output
// written once, epilogue fused. No global atomics, no LDS.
// ---------------------------------------------------------------------------
__global__ __launch_bounds__(256) void gather_kernel(
    const int* __restrict__ cur, const uint2* __restrict__ bins,
    const unsigned* __restrict__ sup, float* __restrict__ out)
{
    const int wave = threadIdx.x >> 6;
    const int col = threadIdx.x & 63;
    const int n = blockIdx.x * 4 + wave;

    int cnt = cur[n];
    if (cnt > CAP) cnt = CAP;
    uint2 p = make_uint2(0u, 0u);
    if (col < cnt) p = bins[(size_t)n * CAP + col];

    float accM = 0.0f, accV = 0.0f;
    for (int i = 0; i < cnt; i += 4) {
        const bool v1 = (i + 1 < cnt), v2 = (i + 2 < cnt), v3 = (i + 3 < cnt);
        int s0 = rl_i(p.x, i);
        int s1 = v1 ? rl_i(p.x, i + 1) : 0;
        int s2 = v2 ? rl_i(p.x, i + 2) : 0;
        int s3 = v3 ? rl_i(p.x, i + 3) : 0;
        float w0 = __uint_as_float((unsigned)rl_i(p.y, i));
        float w1 = v1 ? __uint_as_float((unsigned)rl_i(p.y, i + 1)) : 0.0f;
        float w2 = v2 ? __uint_as_float((unsigned)rl_i(p.y, i + 2)) : 0.0f;
        float w3 = v3 ? __uint_as_float((unsigned)rl_i(p.y, i + 3)) : 0.0f;
        unsigned q0 = sup[(size_t)s0 * CH + col];
        unsigned q1 = sup[(size_t)s1 * CH + col];
        unsigned q2 = sup[(size_t)s2 * CH + col];
        unsigned q3 = sup[(size_t)s3 * CH + col];
        float m0 = __uint_as_float(q0 << 16), vv0 = __uint_as_float(q0 & 0xFFFF0000u);
        float m1 = __uint_as_float(q1 << 16), vv1 = __uint_as_float(q1 & 0xFFFF0000u);
        float m2 = __uint_as_float(q2 << 16), vv2 = __uint_as_float(q2 & 0xFFFF0000u);
        float m3 = __uint_as_float(q3 << 16), vv3 = __uint_as_float(q3 & 0xFFFF0000u);
        accM += w0 * m0 + w1 * m1;
        accM += w2 * m2 + w3 * m3;
        accV += (w0 * w0) * vv0 + (w1 * w1) * vv1;
        accV += (w2 * w2) * vv2 + (w3 * w3) * vv3;
    }
    out[(size_t)n * CH + col] = accM;
    out[OUT_OFF_STD + (size_t)n * CH + col] = sqrtf(expf(accV) + 1e-6f);
}

extern "C" void kernel_launch(void* const* d_in, const int* in_sizes, int n_in,
                              void* d_out, int out_size, void* d_ws, size_t ws_size,
                              hipStream_t stream)
{
    const float* mean  = (const float*)d_in[0];
    const float* stdv  = (const float*)d_in[1];
    const int*   ei    = (const int*)d_in[2];
    const float* ew    = (const float*)d_in[3];
    const float* mu_m  = (const float*)d_in[4];
    const float* ls_m  = (const float*)d_in[5];
    const float* eps_m = (const float*)d_in[6];
    const float* mu_s  = (const float*)d_in[7];
    const float* ls_s  = (const float*)d_in[8];
    const float* eps_s = (const float*)d_in[9];

    float* out = (float*)d_out;
    float* ws  = (float*)d_ws;
    int*      cur  = (int*)ws;                       // 50000 i
    unsigned* sup  = (unsigned*)(ws + 50000);        // 3.2M u32 (12.8 MB)
    uint2*    bins = (uint2*)(ws + 50000 + 6400000); // wait—sup is 3.2M u32

    // layout: cur[50000] | sup[3,200,000 u32] | bins[3,200,000 uint2]
    sup  = (unsigned*)(cur + N_NODES);
    bins = (uint2*)(sup + (size_t)N_NODES * CH);

    hipMemsetAsync(cur, 0, N_NODES * sizeof(int), stream);

    gemfill_kernel<<<6250, 256, 0, stream>>>(mean, stdv,
                                             mu_m, ls_m, eps_m,
                                             mu_s, ls_s, eps_s,
                                             ei, ew, cur, bins, sup,
                                             out + OUT_OFF_KL);
    gather_kernel<<<N_NODES / 4, 256, 0, stream>>>(cur, bins, sup, out);
}

// Round 8
// 205.272 us; speedup vs baseline: 1.2952x; 1.0311x over previous
//
#include <hip/hip_runtime.h>

#define N_NODES 50000
#define N_EDGES 800000
#define CH 64
#define OUT_OFF_STD (N_NODES * CH)        // 3,200,000
#define OUT_OFF_KL  (2 * N_NODES * CH)    // 6,400,000
#define CAP 64                            // slots/node; in-degree ~Poisson(16)
#define GEMM_BLOCKS 782                   // ceil(50000/64); last block: 1 wave
#define FILL_BLOCKS 3125                  // 3125*256 = 800000 exact

typedef __attribute__((ext_vector_type(8))) short short8;
typedef __attribute__((ext_vector_type(4))) float f32x4;

__device__ __forceinline__ int rl_i(unsigned v, int lane) {
    return __builtin_amdgcn_readlane((int)v, lane);
}
// fp32 -> bf16 round-to-nearest-even (returns low 16 bits)
__device__ __forceinline__ unsigned f2bf(float f) {
    unsigned u = __float_as_uint(f);
    return (u + 0x7fffu + ((u >> 16) & 1u)) >> 16;
}

// ---------------------------------------------------------------------------
// Kernel A: reparameterized W -> bf16, PRE-SWIZZLED into MFMA B-fragment
// order: fragB[((c*2+h)*64 + lane)*8 + j] = bf16(W[h*32 + (lane>>4)*8 + j]
//                                                [c*16 + (lane&15)])
// so gemm waves load B-frags as coalesced dwordx4. f<->(k,n) is a bijection,
// so KL rides along visiting each element once. One block, 256 threads.
// ---------------------------------------------------------------------------
__global__ __launch_bounds__(256) void wkl_kernel(
    const float* __restrict__ mu_m, const float* __restrict__ ls_m,
    const float* __restrict__ eps_m,
    const float* __restrict__ mu_s, const float* __restrict__ ls_s,
    const float* __restrict__ eps_s,
    unsigned short* __restrict__ fragBm, unsigned short* __restrict__ fragBv,
    float* __restrict__ kl_out)
{
    float kl = 0.0f;
    for (int f = threadIdx.x; f < CH * CH; f += 256) {
        int j = f & 7, l = (f >> 3) & 63, ch = f >> 9;   // ch = c*2 + h
        int k = (ch & 1) * 32 + ((l >> 4) & 3) * 8 + j;
        int n = (ch >> 1) * 16 + (l & 15);
        int idx = k * CH + n;
        float mu = mu_m[idx], ls = ls_m[idx];
        fragBm[f] = (unsigned short)f2bf(mu + eps_m[idx] * expf(ls));
        kl += 0.5f * (expf(2.0f * ls) + mu * mu - 2.0f * ls - 1.0f);
        mu = mu_s[idx]; ls = ls_s[idx];
        fragBv[f] = (unsigned short)f2bf(mu + eps_s[idx] * expf(ls));
        kl += 0.5f * (expf(2.0f * ls) + mu * mu - 2.0f * ls - 1.0f);
    }
    for (int off = 32; off > 0; off >>= 1)
        kl += __shfl_down(kl, off, 64);
    __shared__ float red[4];
    if ((threadIdx.x & 63) == 0) red[threadIdx.x >> 6] = kl;
    __syncthreads();
    if (threadIdx.x == 0)
        kl_out[0] = red[0] + red[1] + red[2] + red[3];
}

// ---------------------------------------------------------------------------
// Kernel B: fused MFMA-GEMM + fill. ZERO LDS (occupancy = VGPR-bound only).
//  blocks [0, 782): 64 rows, one 16x64 output tile per wave via 16x
//    mfma_f32_16x16x32_bf16 (4 col-tiles x 2 k-halves x 2 matrices).
//    A-frags from global (2 float4/lane/frag), B-frags coalesced dwordx4.
//    Output packed {bf16 mean_sup | bf16 var_sup} in one dword.
//  blocks [782, 3907): 256-edge fill chunk -> per-dst bins.
// ---------------------------------------------------------------------------
__global__ __launch_bounds__(256) void gemfill_kernel(
    const float* __restrict__ mean, const float* __restrict__ stdv,
    const unsigned short* __restrict__ fragBm,
    const unsigned short* __restrict__ fragBv,
    const int* __restrict__ ei, const float* __restrict__ ew,
    int* __restrict__ cur, uint2* __restrict__ bins,
    unsigned* __restrict__ sup)
{
    const int tid = threadIdx.x;

    if (blockIdx.x >= GEMM_BLOCKS) {     // ---- fill role ----
        int e = (blockIdx.x - GEMM_BLOCKS) * 256 + tid;
        int src = ei[e];
        int dst = ei[N_EDGES + e];
        float w = ew[e];
        int slot = atomicAdd(&cur[dst], 1);
        if (slot < CAP)
            bins[(size_t)dst * CAP + slot] =
                make_uint2((unsigned)src, __float_as_uint(w));
        return;
    }

    // ---- gemm role ----
    const int lane = tid & 63, wave = tid >> 6;
    const int row0 = blockIdx.x * 64 + wave * 16;
    if (row0 >= N_NODES) return;         // partial last block, no LDS: safe

    const int m = lane & 15;             // A row within tile
    const int q = (lane >> 4) & 3;       // k quad
    const float* mrow = mean + (size_t)(row0 + m) * CH + q * 8;
    const float* srow = stdv + (size_t)(row0 + m) * CH + q * 8;

    short8 aM[2], aV[2];
#pragma unroll
    for (int h = 0; h < 2; ++h) {        // k-half: k = h*32 + q*8 + j
        float4 x0 = *(const float4*)(mrow + h * 32);
        float4 x1 = *(const float4*)(mrow + h * 32 + 4);
        float4 s0 = *(const float4*)(srow + h * 32);
        float4 s1 = *(const float4*)(srow + h * 32 + 4);
        aM[h][0] = (short)f2bf(x0.x); aM[h][1] = (short)f2bf(x0.y);
        aM[h][2] = (short)f2bf(x0.z); aM[h][3] = (short)f2bf(x0.w);
        aM[h][4] = (short)f2bf(x1.x); aM[h][5] = (short)f2bf(x1.y);
        aM[h][6] = (short)f2bf(x1.z); aM[h][7] = (short)f2bf(x1.w);
        aV[h][0] = (short)f2bf(s0.x * s0.x); aV[h][1] = (short)f2bf(s0.y * s0.y);
        aV[h][2] = (short)f2bf(s0.z * s0.z); aV[h][3] = (short)f2bf(s0.w * s0.w);
        aV[h][4] = (short)f2bf(s1.x * s1.x); aV[h][5] = (short)f2bf(s1.y * s1.y);
        aV[h][6] = (short)f2bf(s1.z * s1.z); aV[h][7] = (short)f2bf(s1.w * s1.w);
    }

    f32x4 accM[4], accV[4];
#pragma unroll
    for (int c = 0; c < 4; ++c) {
        accM[c] = (f32x4)0.0f;
        accV[c] = (f32x4)0.0f;
    }
#pragma unroll
    for (int c = 0; c < 4; ++c) {
#pragma unroll
        for (int h = 0; h < 2; ++h) {
            short8 bm = *(const short8*)(fragBm + ((c * 2 + h) * 64 + lane) * 8);
            short8 bv = *(const short8*)(fragBv + ((c * 2 + h) * 64 + lane) * 8);
            accM[c] = __builtin_amdgcn_mfma_f32_16x16x32_bf16(aM[h], bm, accM[c], 0, 0, 0);
            accV[c] = __builtin_amdgcn_mfma_f32_16x16x32_bf16(aV[h], bv, accV[c], 0, 0, 0);
        }
    }

    // C/D layout: col = lane&15, row = (lane>>4)*4 + reg  [m89-verified]
    const int rg = lane >> 4;
#pragma unroll
    for (int c = 0; c < 4; ++c) {
#pragma unroll
        for (int r = 0; r < 4; ++r) {
            int node = row0 + rg * 4 + r;
            sup[(size_t)node * CH + c * 16 + m] =
                f2bf(accM[c][r]) | (f2bf(accV[c][r]) << 16);
        }
    }
}

// ---------------------------------------------------------------------------
// Kernel C: pull-gather (unchanged from R7). One wave per node, lane = ch.
// ---------------------------------------------------------------------------
__global__ __launch_bounds__(256) void gather_kernel(
    const int* __restrict__ cur, const uint2* __restrict__ bins,
    const unsigned* __restrict__ sup, float* __restrict__ out)
{
    const int wave = threadIdx.x >> 6;
    const int col = threadIdx.x & 63;
    const int n = blockIdx.x * 4 + wave;

    int cnt = cur[n];
    if (cnt > CAP) cnt = CAP;
    uint2 p = make_uint2(0u, 0u);
    if (col < cnt) p = bins[(size_t)n * CAP + col];

    float accM = 0.0f, accV = 0.0f;
    for (int i = 0; i < cnt; i += 4) {
        const bool v1 = (i + 1 < cnt), v2 = (i + 2 < cnt), v3 = (i + 3 < cnt);
        int s0 = rl_i(p.x, i);
        int s1 = v1 ? rl_i(p.x, i + 1) : 0;
        int s2 = v2 ? rl_i(p.x, i + 2) : 0;
        int s3 = v3 ? rl_i(p.x, i + 3) : 0;
        float w0 = __uint_as_float((unsigned)rl_i(p.y, i));
        float w1 = v1 ? __uint_as_float((unsigned)rl_i(p.y, i + 1)) : 0.0f;
        float w2 = v2 ? __uint_as_float((unsigned)rl_i(p.y, i + 2)) : 0.0f;
        float w3 = v3 ? __uint_as_float((unsigned)rl_i(p.y, i + 3)) : 0.0f;
        unsigned q0 = sup[(size_t)s0 * CH + col];
        unsigned q1 = sup[(size_t)s1 * CH + col];
        unsigned q2 = sup[(size_t)s2 * CH + col];
        unsigned q3 = sup[(size_t)s3 * CH + col];
        float m0 = __uint_as_float(q0 << 16), vv0 = __uint_as_float(q0 & 0xFFFF0000u);
        float m1 = __uint_as_float(q1 << 16), vv1 = __uint_as_float(q1 & 0xFFFF0000u);
        float m2 = __uint_as_float(q2 << 16), vv2 = __uint_as_float(q2 & 0xFFFF0000u);
        float m3 = __uint_as_float(q3 << 16), vv3 = __uint_as_float(q3 & 0xFFFF0000u);
        accM += w0 * m0 + w1 * m1;
        accM += w2 * m2 + w3 * m3;
        accV += (w0 * w0) * vv0 + (w1 * w1) * vv1;
        accV += (w2 * w2) * vv2 + (w3 * w3) * vv3;
    }
    out[(size_t)n * CH + col] = accM;
    out[OUT_OFF_STD + (size_t)n * CH + col] = sqrtf(expf(accV) + 1e-6f);
}

extern "C" void kernel_launch(void* const* d_in, const int* in_sizes, int n_in,
                              void* d_out, int out_size, void* d_ws, size_t ws_size,
                              hipStream_t stream)
{
    const float* mean  = (const float*)d_in[0];
    const float* stdv  = (const float*)d_in[1];
    const int*   ei    = (const int*)d_in[2];
    const float* ew    = (const float*)d_in[3];
    const float* mu_m  = (const float*)d_in[4];
    const float* ls_m  = (const float*)d_in[5];
    const float* eps_m = (const float*)d_in[6];
    const float* mu_s  = (const float*)d_in[7];
    const float* ls_s  = (const float*)d_in[8];
    const float* eps_s = (const float*)d_in[9];

    float* out = (float*)d_out;
    // layout (all 16B-aligned): cur | sup | bins | fragBm | fragBv
    int*            cur    = (int*)d_ws;                         // 50000 i
    unsigned*       sup    = (unsigned*)(cur + N_NODES);         // 3.2M u32
    uint2*          bins   = (uint2*)(sup + (size_t)N_NODES * CH); // 3.2M uint2
    unsigned short* fragBm = (unsigned short*)(bins + (size_t)N_NODES * CAP);
    unsigned short* fragBv = fragBm + CH * CH;

    hipMemsetAsync(cur, 0, N_NODES * sizeof(int), stream);

    wkl_kernel<<<1, 256, 0, stream>>>(mu_m, ls_m, eps_m, mu_s, ls_s, eps_s,
                                      fragBm, fragBv, out + OUT_OFF_KL);
    gemfill_kernel<<<GEMM_BLOCKS + FILL_BLOCKS, 256, 0, stream>>>(
        mean, stdv, fragBm, fragBv, ei, ew, cur, bins, sup);
    gather_kernel<<<N_NODES / 4, 256, 0, stream>>>(cur, bins, sup, out);
}

// Round 9
// 190.251 us; speedup vs baseline: 1.3975x; 1.0790x over previous
//
#include <hip/hip_runtime.h>

#define N_NODES 50000
#define N_EDGES 800000
#define CH 64
#define OUT_OFF_STD (N_NODES * CH)        // 3,200,000
#define OUT_OFF_KL  (2 * N_NODES * CH)    // 6,400,000
#define CAP 64                            // slots/node; in-degree ~Poisson(16)

#define NGRP 8                            // XCD groups (blockIdx & 7 heuristic)
#define NPG 6250                          // nodes per group (8*6250 = 50000)
#define FILL_CHUNK 2048
#define FILL_CHUNKS 391                   // 391*2048 = 800768 >= 800000
#define FILL_BLOCKS (NGRP * FILL_CHUNKS)  // 3128
#define GEMM_BLOCKS 782                   // ceil(50000/64)
#define GATHER_CHUNKS 1563                // ceil(6250/4)

typedef __attribute__((ext_vector_type(8))) short short8;
typedef __attribute__((ext_vector_type(4))) float f32x4;

__device__ __forceinline__ int rl_i(unsigned v, int lane) {
    return __builtin_amdgcn_readlane((int)v, lane);
}
// fp32 -> bf16 round-to-nearest-even (returns low 16 bits)
__device__ __forceinline__ unsigned f2bf(float f) {
    unsigned u = __float_as_uint(f);
    return (u + 0x7fffu + ((u >> 16) & 1u)) >> 16;
}

// ---------------------------------------------------------------------------
// Kernel A: W + KL. COALESCED global reads -> LDS; swizzled B-frag layout
// written from LDS (coalesced stores, scattered LDS reads = cheap).
// fragB[((c*2+h)*64 + lane)*8 + j] = bf16(W[h*32+(lane>>4)*8+j][c*16+(lane&15)])
// ---------------------------------------------------------------------------
__global__ __launch_bounds__(256) void wkl_kernel(
    const float* __restrict__ mu_m, const float* __restrict__ ls_m,
    const float* __restrict__ eps_m,
    const float* __restrict__ mu_s, const float* __restrict__ ls_s,
    const float* __restrict__ eps_s,
    unsigned short* __restrict__ fragBm, unsigned short* __restrict__ fragBv,
    float* __restrict__ kl_out)
{
    __shared__ unsigned short Wm[CH * CH];
    __shared__ unsigned short Wv[CH * CH];
    float kl = 0.0f;
    for (int i = threadIdx.x; i < CH * CH; i += 256) {
        float mu = mu_m[i], ls = ls_m[i];
        Wm[i] = (unsigned short)f2bf(mu + eps_m[i] * expf(ls));
        kl += 0.5f * (expf(2.0f * ls) + mu * mu - 2.0f * ls - 1.0f);
        mu = mu_s[i]; ls = ls_s[i];
        Wv[i] = (unsigned short)f2bf(mu + eps_s[i] * expf(ls));
        kl += 0.5f * (expf(2.0f * ls) + mu * mu - 2.0f * ls - 1.0f);
    }
    __syncthreads();
    for (int f = threadIdx.x; f < CH * CH; f += 256) {
        int j = f & 7, l = (f >> 3) & 63, ch = f >> 9;   // ch = c*2 + h
        int k = (ch & 1) * 32 + ((l >> 4) & 3) * 8 + j;
        int n = (ch >> 1) * 16 + (l & 15);
        fragBm[f] = Wm[k * CH + n];
        fragBv[f] = Wv[k * CH + n];
    }
    for (int off = 32; off > 0; off >>= 1)
        kl += __shfl_down(kl, off, 64);
    __shared__ float red[4];
    if ((threadIdx.x & 63) == 0) red[threadIdx.x >> 6] = kl;
    __syncthreads();
    if (threadIdx.x == 0)
        kl_out[0] = red[0] + red[1] + red[2] + red[3];
}

// ---------------------------------------------------------------------------
// Kernel B: fused XCD-affine fill + MFMA-GEMM. Zero LDS.
//  blocks [0, 3128): fill. g = blockIdx&7 -> XCD (round-robin heuristic);
//    scan chunk's dst coalesced, process only dst in own 6250-node range.
//    All bin-line stores for a node then come from ONE XCD -> write-back
//    coalesces in that XCD's L2 -> ~1 writeback/line instead of 1/store.
//  blocks [3128, 3910): 64-row MFMA GEMM tile (16x mfma_16x16x32_bf16/wave),
//    sup packed {bf16 mean | bf16 var} per (node,ch).
// ---------------------------------------------------------------------------
__global__ __launch_bounds__(256) void gemfill_kernel(
    const float* __restrict__ mean, const float* __restrict__ stdv,
    const unsigned short* __restrict__ fragBm,
    const unsigned short* __restrict__ fragBv,
    const int* __restrict__ ei, const float* __restrict__ ew,
    int* __restrict__ cur, uint2* __restrict__ bins,
    unsigned* __restrict__ sup)
{
    const int tid = threadIdx.x;

    if (blockIdx.x < FILL_BLOCKS) {      // ---- fill role, XCD-affine ----
        const int g = blockIdx.x & (NGRP - 1);
        const int chunk = blockIdx.x >> 3;
        const int base = chunk * FILL_CHUNK;
        const int lo = g * NPG;
#pragma unroll
        for (int r = 0; r < FILL_CHUNK / 256; ++r) {
            int e = base + r * 256 + tid;
            if (e < N_EDGES) {
                int dst = ei[N_EDGES + e];
                if ((unsigned)(dst - lo) < (unsigned)NPG) {
                    int src = ei[e];
                    float w = ew[e];
                    int slot = atomicAdd(&cur[dst], 1);
                    if (slot < CAP)
                        bins[(size_t)dst * CAP + slot] =
                            make_uint2((unsigned)src, __float_as_uint(w));
                }
            }
        }
        return;
    }

    // ---- gemm role ----
    const int lane = tid & 63, wave = tid >> 6;
    const int row0 = (blockIdx.x - FILL_BLOCKS) * 64 + wave * 16;
    if (row0 >= N_NODES) return;

    const int m = lane & 15;             // A row within tile
    const int q = (lane >> 4) & 3;       // k quad
    const float* mrow = mean + (size_t)(row0 + m) * CH + q * 8;
    const float* srow = stdv + (size_t)(row0 + m) * CH + q * 8;

    short8 aM[2], aV[2];
#pragma unroll
    for (int h = 0; h < 2; ++h) {        // k = h*32 + q*8 + j
        float4 x0 = *(const float4*)(mrow + h * 32);
        float4 x1 = *(const float4*)(mrow + h * 32 + 4);
        float4 s0 = *(const float4*)(srow + h * 32);
        float4 s1 = *(const float4*)(srow + h * 32 + 4);
        aM[h][0] = (short)f2bf(x0.x); aM[h][1] = (short)f2bf(x0.y);
        aM[h][2] = (short)f2bf(x0.z); aM[h][3] = (short)f2bf(x0.w);
        aM[h][4] = (short)f2bf(x1.x); aM[h][5] = (short)f2bf(x1.y);
        aM[h][6] = (short)f2bf(x1.z); aM[h][7] = (short)f2bf(x1.w);
        aV[h][0] = (short)f2bf(s0.x * s0.x); aV[h][1] = (short)f2bf(s0.y * s0.y);
        aV[h][2] = (short)f2bf(s0.z * s0.z); aV[h][3] = (short)f2bf(s0.w * s0.w);
        aV[h][4] = (short)f2bf(s1.x * s1.x); aV[h][5] = (short)f2bf(s1.y * s1.y);
        aV[h][6] = (short)f2bf(s1.z * s1.z); aV[h][7] = (short)f2bf(s1.w * s1.w);
    }

    f32x4 accM[4], accV[4];
#pragma unroll
    for (int c = 0; c < 4; ++c) {
        accM[c] = (f32x4)0.0f;
        accV[c] = (f32x4)0.0f;
    }
#pragma unroll
    for (int c = 0; c < 4; ++c) {
#pragma unroll
        for (int h = 0; h < 2; ++h) {
            short8 bm = *(const short8*)(fragBm + ((c * 2 + h) * 64 + lane) * 8);
            short8 bv = *(const short8*)(fragBv + ((c * 2 + h) * 64 + lane) * 8);
            accM[c] = __builtin_amdgcn_mfma_f32_16x16x32_bf16(aM[h], bm, accM[c], 0, 0, 0);
            accV[c] = __builtin_amdgcn_mfma_f32_16x16x32_bf16(aV[h], bv, accV[c], 0, 0, 0);
        }
    }

    // C/D layout: col = lane&15, row = (lane>>4)*4 + reg  [m89-verified]
    const int rg = lane >> 4;
#pragma unroll
    for (int c = 0; c < 4; ++c) {
#pragma unroll
        for (int r = 0; r < 4; ++r) {
            int node = row0 + rg * 4 + r;
            sup[(size_t)node * CH + c * 16 + m] =
                f2bf(accM[c][r]) | (f2bf(accV[c][r]) << 16);
        }
    }
}

// ---------------------------------------------------------------------------
// Kernel C: pull-gather, XCD-affine (same g = blockIdx&7 mapping as fill, so
// a group's bins/cur are L2-resident on its XCD). One wave per node, lane =
// channel, 8 independent sup loads in flight per iter. No atomics, no LDS.
// ---------------------------------------------------------------------------
__global__ __launch_bounds__(256) void gather_kernel(
    const int* __restrict__ cur, const uint2* __restrict__ bins,
    const unsigned* __restrict__ sup, float* __restrict__ out)
{
    const int g = blockIdx.x & (NGRP - 1);
    const int cid = blockIdx.x >> 3;
    const int wave = threadIdx.x >> 6;
    const int col = threadIdx.x & 63;
    const int loc = cid * 4 + wave;
    if (loc >= NPG) return;
    const int n = g * NPG + loc;

    int cnt = cur[n];
    if (cnt > CAP) cnt = CAP;
    uint2 p = make_uint2(0u, 0u);
    if (col < cnt) p = bins[(size_t)n * CAP + col];

    float accM = 0.0f, accV = 0.0f;
    for (int i = 0; i < cnt; i += 8) {
        int   s[8];
        float w[8];
#pragma unroll
        for (int t = 0; t < 8; ++t) {
            bool v = (i + t < cnt);
            s[t] = v ? rl_i(p.x, i + t) : 0;
            w[t] = v ? __uint_as_float((unsigned)rl_i(p.y, i + t)) : 0.0f;
        }
        unsigned q[8];
#pragma unroll
        for (int t = 0; t < 8; ++t)
            q[t] = sup[(size_t)s[t] * CH + col];
#pragma unroll
        for (int t = 0; t < 8; ++t) {
            float mm = __uint_as_float(q[t] << 16);
            float vv = __uint_as_float(q[t] & 0xFFFF0000u);
            accM += w[t] * mm;
            accV += (w[t] * w[t]) * vv;
        }
    }
    out[(size_t)n * CH + col] = accM;
    out[OUT_OFF_STD + (size_t)n * CH + col] = sqrtf(expf(accV) + 1e-6f);
}

extern "C" void kernel_launch(void* const* d_in, const int* in_sizes, int n_in,
                              void* d_out, int out_size, void* d_ws, size_t ws_size,
                              hipStream_t stream)
{
    const float* mean  = (const float*)d_in[0];
    const float* stdv  = (const float*)d_in[1];
    const int*   ei    = (const int*)d_in[2];
    const float* ew    = (const float*)d_in[3];
    const float* mu_m  = (const float*)d_in[4];
    const float* ls_m  = (const float*)d_in[5];
    const float* eps_m = (const float*)d_in[6];
    const float* ls_s  = (const float*)d_in[8];
    const float* mu_s  = (const float*)d_in[7];
    const float* eps_s = (const float*)d_in[9];

    float* out = (float*)d_out;
    // layout (16B-aligned): cur | sup | bins | fragBm | fragBv
    int*            cur    = (int*)d_ws;                           // 50000 i
    unsigned*       sup    = (unsigned*)(cur + N_NODES);           // 3.2M u32
    uint2*          bins   = (uint2*)(sup + (size_t)N_NODES * CH); // 3.2M uint2
    unsigned short* fragBm = (unsigned short*)(bins + (size_t)N_NODES * CAP);
    unsigned short* fragBv = fragBm + CH * CH;

    hipMemsetAsync(cur, 0, N_NODES * sizeof(int), stream);

    wkl_kernel<<<1, 256, 0, stream>>>(mu_m, ls_m, eps_m, mu_s, ls_s, eps_s,
                                      fragBm, fragBv, out + OUT_OFF_KL);
    gemfill_kernel<<<FILL_BLOCKS + GEMM_BLOCKS, 256, 0, stream>>>(
        mean, stdv, fragBm, fragBv, ei, ew, cur, bins, sup);
    gather_kernel<<<NGRP * GATHER_CHUNKS, 256, 0, stream>>>(cur, bins, sup, out);
}